// Round 2
// baseline (122.148 us; speedup 1.0000x reference)
//
#include <hip/hip_runtime.h>

// DAREController route(is_visual=True, training=True)
// B=256 rows, S=32768 tokens. One block per row.
//
// R8 -> R9: parallel 3-level radix select (R8) + early/deferred store overlap (R7).
//  - Level 0: 2048-bin histogram on key bits [31:21], 4 bank-staggered copies.
//  - After the level-0 scan, elements with bucket != b0 are DECIDED: their
//    vec4s are stored immediately (~97% of the 128 KB/row write stream), so
//    the HBM write drain overlaps levels 1-2 of the select.
//  - Level 1 (bits [20:10], ~600 candidates/block) histogram is built in the
//    same pass; level 2 (bits [9:0], ~1-2 candidates) gives the EXACT
//    threshold. No candidate array, no serial wave-0 finisher.
//  - Deferred vec4s (those containing a bucket-b0 candidate, ~0.6/thread) are
//    stored in a tiny tail with the exact threshold.
//  - All candidate loops use compile-time indices (predicated) -- runtime
//    indexing of keys[] would spill the register array to scratch.

#define NB 256
#define NS 32768
#define KAPPA 64
#define NT 1024
#define V4 (NS / NT / 4)      // 8 vec4 per thread
#define NCOPY 4               // level-0 histogram copies
#define NBIN0 2048            // key bits [31:21]
#define PAD0 8                // stagger copies by 8 banks
#define NBIN1 2048            // key bits [20:10]
#define NBIN2 1024            // key bits [9:0]
#define NSEG 256              // scan threads

typedef float f32x4 __attribute__((ext_vector_type(4)));
typedef int   i32x4 __attribute__((ext_vector_type(4)));

__device__ __forceinline__ unsigned int fkey(float f) {
    unsigned int u = __float_as_uint(f);
    return (u & 0x80000000u) ? ~u : (u | 0x80000000u);  // monotone: bigger float -> bigger key
}

__device__ __forceinline__ float unkey(unsigned int k) {
    unsigned int u = (k & 0x80000000u) ? (k ^ 0x80000000u) : ~k;
    return __uint_as_float(u);
}

// Descending (k-th largest) crossing-bin search over NSEG segments x SEGW bins.
// Caller supplies per-thread bin counts r[] and their sum hsum (tid<NSEG only),
// plus rem (k-th from the top). Writes *out_bin / *out_rem in the crossing
// thread. Contains ONE internal barrier; caller must barrier after.
template <int SEGW>
__device__ __forceinline__ void scan_find(const unsigned int (&r)[SEGW], unsigned int hsum,
                                          unsigned int rem, unsigned int* wtot,
                                          unsigned int* out_bin, unsigned int* out_rem,
                                          const int tid, const int lane, const int wid) {
    unsigned int s = 0;
    if (tid < NSEG) {
        s = hsum;
        #pragma unroll
        for (int off = 1; off < 64; off <<= 1) {       // suffix-sum within wave
            const unsigned int t = __shfl_down(s, off);
            if (lane + off < 64) s += t;
        }
        if (lane == 0) wtot[wid] = s;
    }
    __syncthreads();                                   // wtot ready
    if (tid < NSEG) {
        unsigned int sfull = s;
        for (int w = wid + 1; w < 4; w++) sfull += wtot[w];
        const unsigned int above = sfull - hsum;       // count in higher segments
        if (sfull >= rem && above < rem) {             // crossing segment
            unsigned int cum = above;
            #pragma unroll
            for (int b = SEGW - 1; b >= 0; b--) {
                if (cum + r[b] >= rem) { *out_bin = (unsigned int)(tid * SEGW + b); *out_rem = rem - cum; break; }
                cum += r[b];
            }
        }
    }
}

__global__ __launch_bounds__(NT) void dare_rows(const float* __restrict__ imp,
                                                const int* __restrict__ mask,
                                                float* __restrict__ keep,
                                                float* __restrict__ stats) {
    __shared__ unsigned int hist0[NCOPY][NBIN0 + PAD0];  // ~32.9 KB
    __shared__ unsigned int hist1[NBIN1];                // 8 KB
    __shared__ unsigned int hist2[NBIN2];                // 4 KB
    __shared__ unsigned int wtot[4];
    __shared__ unsigned int sh_mm, sh_eff;
    __shared__ unsigned int sh_b0, sh_rem0, sh_b1, sh_rem1, sh_thresh;
    __shared__ unsigned int sh_kept, sh_ndrop;
    __shared__ float sh_dsum;

    const int row = blockIdx.x;
    const int tid = threadIdx.x;
    const int lane = tid & 63;
    const int wid = tid >> 6;
    const f32x4* rimp4  = (const f32x4*)(imp  + (size_t)row * NS);
    const i32x4* rmask4 = (const i32x4*)(mask + (size_t)row * NS);
    f32x4*       rkeep4 = (f32x4*)      (keep + (size_t)row * NS);

    #pragma unroll
    for (int c = 0; c < NCOPY; c++) { hist0[c][tid] = 0; hist0[c][tid + NT] = 0; }
    hist1[tid] = 0; hist1[tid + NT] = 0;
    hist2[tid] = 0;
    if (tid == 0) {
        sh_mm = 0; sh_eff = 0;
        sh_b0 = 0; sh_rem0 = 1; sh_b1 = 0; sh_rem1 = 1; sh_thresh = 0;
        sh_kept = 0; sh_ndrop = 0; sh_dsum = 0.0f;
    }
    __syncthreads();   // B1

    // ---- Phase 1: one streaming read -> keys in regs + level-0 histogram ----
    unsigned int keys[V4 * 4];
    unsigned int effbits = 0, mmbits = 0;
    const int hc = wid & (NCOPY - 1);

    #pragma unroll
    for (int i = 0; i < V4; i++) {
        const int idx4 = tid + i * NT;
        const f32x4 v = __builtin_nontemporal_load(&rimp4[idx4]);
        const i32x4 m = __builtin_nontemporal_load(&rmask4[idx4]);
        #pragma unroll
        for (int j = 0; j < 4; j++) {
            const int e = i * 4 + j;
            const int col = idx4 * 4 + j;
            keys[e] = fkey(v[j]);
            const bool mm  = (m[j] != 0);
            const bool eff = mm && (col >= KAPPA);
            mmbits  |= (mm  ? 1u : 0u) << e;
            effbits |= (eff ? 1u : 0u) << e;
        }
    }
    #pragma unroll
    for (int e = 0; e < V4 * 4; e++) {
        if ((effbits >> e) & 1u) atomicAdd(&hist0[hc][keys[e] >> 21], 1u);
    }

    int mm_local  = __popc(mmbits);
    int eff_local = __popc(effbits);
    #pragma unroll
    for (int off = 32; off; off >>= 1) {
        mm_local  += __shfl_down(mm_local, off);
        eff_local += __shfl_down(eff_local, off);
    }
    if (lane == 0) {
        atomicAdd(&sh_mm,  (unsigned int)mm_local);
        atomicAdd(&sh_eff, (unsigned int)eff_local);
    }
    __syncthreads();   // B2 (hist0 + counts ready)

    // ---- Level 0 scan: bits [31:21] ----
    {
        unsigned int r0[NBIN0 / NSEG] = {};
        unsigned int hsum = 0;
        if (tid < NSEG) {
            #pragma unroll
            for (int b = 0; b < NBIN0 / NSEG; b++) {
                unsigned int v = 0;
                #pragma unroll
                for (int c = 0; c < NCOPY; c++) v += hist0[c][tid * (NBIN0 / NSEG) + b];
                r0[b] = v; hsum += v;
            }
        }
        const float target = fmaxf((float)sh_mm * 0.5f, 1.0f);
        const int k = min((int)target, (int)sh_eff);
        const unsigned int rem = (unsigned int)max(k, 1);
        scan_find<NBIN0 / NSEG>(r0, hsum, rem, wtot, &sh_b0, &sh_rem0, tid, lane, wid);  // B3 inside
    }
    __syncthreads();   // B4 (b0, rem0 ready)

    // ---- Phase E: early stores for decided vec4s + level-1 histogram ----
    const unsigned int b0 = sh_b0;
    const bool kpos = (sh_eff > 0);

    int kept_l = 0, ndrop_l = 0;
    float dsum_l = 0.0f;

    unsigned int candbits = 0;
    if (kpos) {
        #pragma unroll
        for (int e = 0; e < V4 * 4; e++) {
            if (((effbits >> e) & 1u) && (keys[e] >> 21) == b0) candbits |= 1u << e;
        }
    }

    unsigned int defer = 0;
    #pragma unroll
    for (int i = 0; i < V4; i++) {
        if ((candbits >> (4 * i)) & 0xFu) {
            defer |= 1u << i;          // contains an undecided candidate
        } else {
            const int idx4 = tid + i * NT;
            f32x4 o;
            #pragma unroll
            for (int j = 0; j < 4; j++) {
                const int e = i * 4 + j;
                const int col = idx4 * 4 + j;
                const bool mm  = (mmbits >> e) & 1u;
                const bool eff = (effbits >> e) & 1u;
                const bool hard = kpos && eff && ((keys[e] >> 21) > b0);
                const bool kp = (col < KAPPA) || hard;
                o[j] = kp ? 1.0f : 0.0f;
                kept_l += (kp && mm) ? 1 : 0;
                const bool drop = mm && !kp;
                ndrop_l += drop ? 1 : 0;
                dsum_l += drop ? unkey(keys[e]) : 0.0f;
            }
            __builtin_nontemporal_store(o, &rkeep4[idx4]);
        }
    }

    // level-1 histogram over bucket-b0 candidates (~0.6/thread)
    #pragma unroll
    for (int e = 0; e < V4 * 4; e++) {
        if ((candbits >> e) & 1u) atomicAdd(&hist1[(keys[e] >> 10) & (NBIN1 - 1)], 1u);
    }
    __syncthreads();   // B5 (hist1 ready; early stores draining in background)

    // ---- Level 1 scan: bits [20:10] ----
    {
        unsigned int r1[NBIN1 / NSEG] = {};
        unsigned int hsum = 0;
        if (tid < NSEG) {
            #pragma unroll
            for (int b = 0; b < NBIN1 / NSEG; b++) {
                const unsigned int v = hist1[tid * (NBIN1 / NSEG) + b];
                r1[b] = v; hsum += v;
            }
        }
        scan_find<NBIN1 / NSEG>(r1, hsum, sh_rem0, wtot, &sh_b1, &sh_rem1, tid, lane, wid);  // B6 inside
    }
    __syncthreads();   // B7 (b1, rem1 ready)

    // ---- Level 2: bits [9:0] over (b0,b1) candidates (~1-2/block) ----
    const unsigned int b1 = sh_b1;
    const unsigned int top22 = (b0 << 11) | b1;
    #pragma unroll
    for (int e = 0; e < V4 * 4; e++) {
        if (((candbits >> e) & 1u) && (keys[e] >> 10) == top22)
            atomicAdd(&hist2[keys[e] & (NBIN2 - 1)], 1u);
    }
    __syncthreads();   // B8 (hist2 ready)
    {
        unsigned int r2[NBIN2 / NSEG] = {};
        unsigned int hsum = 0;
        if (tid < NSEG) {
            #pragma unroll
            for (int b = 0; b < NBIN2 / NSEG; b++) {
                const unsigned int v = hist2[tid * (NBIN2 / NSEG) + b];
                r2[b] = v; hsum += v;
            }
        }
        unsigned int dummy_rem;
        scan_find<NBIN2 / NSEG>(r2, hsum, sh_rem1, wtot, &sh_thresh, &dummy_rem, tid, lane, wid);  // B9 inside
    }
    __syncthreads();   // B10 (low-10 bin ready)

    // ---- Tail: deferred vec4s with exact threshold ----
    const unsigned int thresh = (top22 << 10) | sh_thresh;
    #pragma unroll
    for (int i = 0; i < V4; i++) {
        if ((defer >> i) & 1u) {
            const int idx4 = tid + i * NT;
            f32x4 o;
            #pragma unroll
            for (int j = 0; j < 4; j++) {
                const int e = i * 4 + j;
                const int col = idx4 * 4 + j;
                const bool mm  = (mmbits >> e) & 1u;
                const bool eff = (effbits >> e) & 1u;
                const bool hard = kpos && eff && (keys[e] >= thresh);
                const bool kp = (col < KAPPA) || hard;
                o[j] = kp ? 1.0f : 0.0f;
                kept_l += (kp && mm) ? 1 : 0;
                const bool drop = mm && !kp;
                ndrop_l += drop ? 1 : 0;
                dsum_l += drop ? unkey(keys[e]) : 0.0f;
            }
            __builtin_nontemporal_store(o, &rkeep4[idx4]);
        }
    }

    #pragma unroll
    for (int off = 32; off; off >>= 1) {
        kept_l  += __shfl_down(kept_l, off);
        ndrop_l += __shfl_down(ndrop_l, off);
        dsum_l  += __shfl_down(dsum_l, off);
    }
    if (lane == 0) {
        atomicAdd(&sh_kept,  (unsigned int)kept_l);
        atomicAdd(&sh_ndrop, (unsigned int)ndrop_l);
        atomicAdd(&sh_dsum,  dsum_l);
    }
    __syncthreads();   // B11
    if (tid == 0) {
        stats[row * 4 + 0] = (float)sh_kept;
        stats[row * 4 + 1] = (float)sh_mm;
        stats[row * 4 + 2] = (float)sh_ndrop;
        stats[row * 4 + 3] = sh_dsum;
    }
}

__global__ __launch_bounds__(256) void dare_losses(const float* __restrict__ stats,
                                                   float* __restrict__ out) {
    __shared__ float w_a[4], w_h[4], w_n[4], w_d[4];
    const int tid = threadIdx.x;   // one thread per row
    const float kept = stats[tid * 4 + 0];
    const float mmc  = stats[tid * 4 + 1];
    const float nd   = stats[tid * 4 + 2];
    const float ds   = stats[tid * 4 + 3];
    const float ratio = kept / (mmc + 1e-6f);
    float a = fabsf(ratio - 0.5f);          // |ratio - rho|
    float h = fmaxf(0.5f - ratio, 0.0f);    // relu(rho - ratio)
    float n = nd, d = ds;
    #pragma unroll
    for (int off = 32; off; off >>= 1) {
        a += __shfl_down(a, off);
        h += __shfl_down(h, off);
        n += __shfl_down(n, off);
        d += __shfl_down(d, off);
    }
    const int wid = tid >> 6, lane = tid & 63;
    if (lane == 0) { w_a[wid] = a; w_h[wid] = h; w_n[wid] = n; w_d[wid] = d; }
    __syncthreads();
    if (tid == 0) {
        float sa = 0.f, shh = 0.f, sn = 0.f, sd = 0.f;
        for (int w = 0; w < 4; w++) { sa += w_a[w]; shh += w_h[w]; sn += w_n[w]; sd += w_d[w]; }
        out[0] = sa / (float)NB;                                        // 1.0 * loss_ratio
        out[1] = (sn > 0.0f) ? 0.1f * (sd / fmaxf(sn, 1.0f)) : 0.0f;    // 0.1 * loss_soft
        out[2] = shh / (float)NB;                                       // 1.0 * loss_hard
    }
}

extern "C" void kernel_launch(void* const* d_in, const int* in_sizes, int n_in,
                              void* d_out, int out_size, void* d_ws, size_t ws_size,
                              hipStream_t stream) {
    const float* imp  = (const float*)d_in[0];
    const int*   mask = (const int*)d_in[1];
    float* out   = (float*)d_out;
    float* stats = (float*)d_ws;   // 256 rows * 4 floats = 4 KB

    dare_rows<<<NB, NT, 0, stream>>>(imp, mask, out, stats);
    dare_losses<<<1, 256, 0, stream>>>(stats, out + (size_t)NB * NS);
}

// Round 3
// 109.558 us; speedup vs baseline: 1.1149x; 1.1149x over previous
//
#include <hip/hip_runtime.h>

// DAREController route(is_visual=True, training=True)
// B=256 rows, S=32768 tokens. One block per row.
//
// R10 = R7 (best verified: single-pass coarse select + wave-0 finisher,
// early/deferred stores, plain loads/stores) with ONE change:
//   level-0 histogram widened 11 -> 12 bits (2048 -> 4096 bins).
//   - halves candidate count (~600 -> ~300/row on N(0,1) data):
//     * wave-0 ballot finisher: ~210 -> ~100 serial ballot steps
//     * sh_cand append-atomic serialization halved
//   - LDS: cand 128 KB + hist 16 KB ~= 144.5 KB (fits; 1 block/CU as before)
// R8/R9's parallel 3-level radix select regressed (112.9 -> 115.1 -> 122.1):
// its fixed overhead (extra barriers/scans/LDS init, divergent NT stores)
// exceeded the ~1-2 us finisher it replaced. Reverted.

#define NB 256
#define NS 32768
#define KAPPA 64
#define NT 1024
#define V4 (NS / NT / 4)      // 8 vec4 per thread
#define NBIN 4096             // top-12-bit buckets
#define NSEG 256              // scan segments (threads)
#define SEGW (NBIN / NSEG)    // 16 bins per scan thread
#define LOWBITS 20            // remaining bits for the finisher
#define LOWMASK 0xFFFFFu

typedef float f32x4 __attribute__((ext_vector_type(4)));
typedef int   i32x4 __attribute__((ext_vector_type(4)));

__device__ __forceinline__ unsigned int fkey(float f) {
    unsigned int u = __float_as_uint(f);
    return (u & 0x80000000u) ? ~u : (u | 0x80000000u);  // monotone: bigger float -> bigger key
}

__device__ __forceinline__ float unkey(unsigned int k) {
    unsigned int u = (k & 0x80000000u) ? (k ^ 0x80000000u) : ~k;
    return __uint_as_float(u);
}

__global__ __launch_bounds__(NT) void dare_rows(const float* __restrict__ imp,
                                                const int* __restrict__ mask,
                                                float* __restrict__ keep,
                                                float* __restrict__ stats) {
    __shared__ unsigned int hist[NBIN];     // 16 KB
    __shared__ unsigned int cand[NS];       // 128 KB: candidate keys (bucket == b0)
    __shared__ unsigned int wtot[4];
    __shared__ unsigned int sh_mm, sh_eff, sh_cand;
    __shared__ unsigned int sh_b0, sh_rem, sh_thresh;
    __shared__ unsigned int sh_kept, sh_ndrop;
    __shared__ float sh_dsum;

    const int row = blockIdx.x;
    const int tid = threadIdx.x;
    const int lane = tid & 63;
    const int wid = tid >> 6;
    const f32x4* rimp4  = (const f32x4*)(imp  + (size_t)row * NS);
    const i32x4* rmask4 = (const i32x4*)(mask + (size_t)row * NS);
    f32x4*       rkeep4 = (f32x4*)      (keep + (size_t)row * NS);

    #pragma unroll
    for (int c = 0; c < NBIN / NT; c++) hist[tid + c * NT] = 0;
    if (tid == 0) {
        sh_mm = 0; sh_eff = 0; sh_cand = 0;
        sh_b0 = 0; sh_rem = 1; sh_thresh = 0;
        sh_kept = 0; sh_ndrop = 0; sh_dsum = 0.0f;
    }
    __syncthreads();   // B1

    // ---- Phase 1: one streaming read -> keys in regs ----
    unsigned int keys[V4 * 4];
    unsigned int effbits = 0, mmbits = 0;

    #pragma unroll
    for (int i = 0; i < V4; i++) {
        const int idx4 = tid + i * NT;
        const f32x4 v = rimp4[idx4];
        const i32x4 m = rmask4[idx4];
        #pragma unroll
        for (int j = 0; j < 4; j++) {
            const int e = i * 4 + j;
            const int col = idx4 * 4 + j;
            keys[e] = fkey(v[j]);
            const bool mm  = (m[j] != 0);
            const bool eff = mm && (col >= KAPPA);
            mmbits  |= (mm  ? 1u : 0u) << e;
            effbits |= (eff ? 1u : 0u) << e;
        }
    }

    // single histogram pass (top 12 bits)
    #pragma unroll
    for (int e = 0; e < V4 * 4; e++) {
        if ((effbits >> e) & 1u) atomicAdd(&hist[keys[e] >> LOWBITS], 1u);
    }

    int mm_local  = __popc(mmbits);
    int eff_local = __popc(effbits);
    #pragma unroll
    for (int off = 32; off; off >>= 1) {
        mm_local  += __shfl_down(mm_local, off);
        eff_local += __shfl_down(eff_local, off);
    }
    if (lane == 0) {
        atomicAdd(&sh_mm,  (unsigned int)mm_local);
        atomicAdd(&sh_eff, (unsigned int)eff_local);
    }
    __syncthreads();   // B2 (hist + counts ready)

    // ---- Phase 2: coarse scan, 256 threads x 16 bins each ----
    unsigned int r[SEGW];
    unsigned int hsum = 0, s = 0;
    if (tid < NSEG) {
        #pragma unroll
        for (int b = 0; b < SEGW; b++) { r[b] = hist[tid * SEGW + b]; hsum += r[b]; }
        s = hsum;
        #pragma unroll
        for (int off = 1; off < 64; off <<= 1) {
            const unsigned int t = __shfl_down(s, off);
            if (lane + off < 64) s += t;
        }
        if (lane == 0) wtot[tid >> 6] = s;
    }
    __syncthreads();   // B3 (wtot ready)
    if (tid < NSEG) {
        unsigned int sfull = s;
        for (int w = (tid >> 6) + 1; w < 4; w++) sfull += wtot[w];
        const float target = fmaxf((float)sh_mm * 0.5f, 1.0f);
        const int k = min((int)target, (int)sh_eff);
        const unsigned int rem = (unsigned int)max(k, 1);
        const unsigned int above = sfull - hsum;   // count in higher segments
        if (sfull >= rem && above < rem) {
            // crossing segment: walk bins high -> low in registers
            unsigned int cum = above;
            #pragma unroll
            for (int b = SEGW - 1; b >= 0; b--) {
                if (cum + r[b] >= rem) { sh_b0 = tid * SEGW + b; sh_rem = rem - cum; break; }
                cum += r[b];
            }
        }
    }
    __syncthreads();   // B4 (b0, rem ready)

    // ---- Phase 3a: early stores for decided vec4s + candidate append ----
    const unsigned int b0 = sh_b0;
    const bool kpos = (sh_eff > 0);

    int kept_l = 0, ndrop_l = 0;
    float dsum_l = 0.0f;
    unsigned int defer = 0;

    #pragma unroll
    for (int i = 0; i < V4; i++) {
        const int idx4 = tid + i * NT;
        unsigned int cm = 0;
        #pragma unroll
        for (int j = 0; j < 4; j++) {
            const int e = i * 4 + j;
            const bool eff = (effbits >> e) & 1u;
            const bool is_cand = kpos && eff && ((keys[e] >> LOWBITS) == b0);
            cm |= (is_cand ? 1u : 0u) << j;
        }
        if (cm) {
            defer |= 1u << i;
            #pragma unroll
            for (int j = 0; j < 4; j++) {
                if ((cm >> j) & 1u) {
                    const unsigned int pos = atomicAdd(&sh_cand, 1u);
                    cand[pos] = keys[i * 4 + j];
                }
            }
        } else {
            f32x4 o;
            #pragma unroll
            for (int j = 0; j < 4; j++) {
                const int e = i * 4 + j;
                const int col = idx4 * 4 + j;
                const bool mm  = (mmbits >> e) & 1u;
                const bool eff = (effbits >> e) & 1u;
                const bool hard = kpos && eff && ((keys[e] >> LOWBITS) > b0);
                const bool kp = (col < KAPPA) || hard;
                o[j] = kp ? 1.0f : 0.0f;
                kept_l += (kp && mm) ? 1 : 0;
                const bool drop = mm && !kp;
                ndrop_l += drop ? 1 : 0;
                dsum_l += drop ? unkey(keys[e]) : 0.0f;
            }
            rkeep4[idx4] = o;
        }
    }
    __syncthreads();   // B5 (cand array complete)

    // ---- Phase 3b: wave-0 ballot bit-select over candidates ----
    if (tid < 64) {
        const unsigned int cnt = sh_cand;
        if (cnt > 0) {
            unsigned int rem = sh_rem;
            unsigned int pref = 0;
            const int slots = (int)((cnt + 63u) >> 6);
            unsigned int lowreg[16];
            #pragma unroll
            for (int sl = 0; sl < 16; sl++) {
                const unsigned int idx = (unsigned int)lane + ((unsigned int)sl << 6);
                lowreg[sl] = (idx < cnt) ? (cand[idx] & LOWMASK) : 0xFFFFFFFFu;
            }
            for (int bit = LOWBITS - 1; bit >= 0; bit--) {
                const unsigned int hi = pref >> (bit + 1);
                unsigned int cnt1 = 0;
                for (int sl = 0; sl < slots; sl++) {
                    unsigned int lw;
                    if (sl < 16) lw = lowreg[sl];
                    else {
                        const unsigned int idx = (unsigned int)lane + ((unsigned int)sl << 6);
                        lw = (idx < cnt) ? (cand[idx] & LOWMASK) : 0xFFFFFFFFu;
                    }
                    const bool m = (lw >> (bit + 1)) == hi && ((lw >> bit) & 1u);
                    cnt1 += (unsigned int)__popcll(__ballot(m));
                }
                if (cnt1 >= rem) pref |= 1u << bit; else rem -= cnt1;
            }
            if (lane == 0) sh_thresh = (b0 << LOWBITS) | pref;
        }
    }
    __syncthreads();   // B6 (thresh ready)

    // ---- Phase 3c: tail — deferred vec4s with exact threshold ----
    const unsigned int thresh = sh_thresh;
    #pragma unroll
    for (int i = 0; i < V4; i++) {
        if ((defer >> i) & 1u) {
            const int idx4 = tid + i * NT;
            f32x4 o;
            #pragma unroll
            for (int j = 0; j < 4; j++) {
                const int e = i * 4 + j;
                const int col = idx4 * 4 + j;
                const bool mm  = (mmbits >> e) & 1u;
                const bool eff = (effbits >> e) & 1u;
                const bool hard = kpos && eff && (keys[e] >= thresh);
                const bool kp = (col < KAPPA) || hard;
                o[j] = kp ? 1.0f : 0.0f;
                kept_l += (kp && mm) ? 1 : 0;
                const bool drop = mm && !kp;
                ndrop_l += drop ? 1 : 0;
                dsum_l += drop ? unkey(keys[e]) : 0.0f;
            }
            rkeep4[idx4] = o;
        }
    }

    #pragma unroll
    for (int off = 32; off; off >>= 1) {
        kept_l  += __shfl_down(kept_l, off);
        ndrop_l += __shfl_down(ndrop_l, off);
        dsum_l  += __shfl_down(dsum_l, off);
    }
    if (lane == 0) {
        atomicAdd(&sh_kept,  (unsigned int)kept_l);
        atomicAdd(&sh_ndrop, (unsigned int)ndrop_l);
        atomicAdd(&sh_dsum,  dsum_l);
    }
    __syncthreads();   // B7
    if (tid == 0) {
        stats[row * 4 + 0] = (float)sh_kept;
        stats[row * 4 + 1] = (float)sh_mm;
        stats[row * 4 + 2] = (float)sh_ndrop;
        stats[row * 4 + 3] = sh_dsum;
    }
}

__global__ __launch_bounds__(256) void dare_losses(const float* __restrict__ stats,
                                                   float* __restrict__ out) {
    __shared__ float w_a[4], w_h[4], w_n[4], w_d[4];
    const int tid = threadIdx.x;   // one thread per row
    const float kept = stats[tid * 4 + 0];
    const float mmc  = stats[tid * 4 + 1];
    const float nd   = stats[tid * 4 + 2];
    const float ds   = stats[tid * 4 + 3];
    const float ratio = kept / (mmc + 1e-6f);
    float a = fabsf(ratio - 0.5f);          // |ratio - rho|
    float h = fmaxf(0.5f - ratio, 0.0f);    // relu(rho - ratio)
    float n = nd, d = ds;
    #pragma unroll
    for (int off = 32; off; off >>= 1) {
        a += __shfl_down(a, off);
        h += __shfl_down(h, off);
        n += __shfl_down(n, off);
        d += __shfl_down(d, off);
    }
    const int wid = tid >> 6, lane = tid & 63;
    if (lane == 0) { w_a[wid] = a; w_h[wid] = h; w_n[wid] = n; w_d[wid] = d; }
    __syncthreads();
    if (tid == 0) {
        float sa = 0.f, shh = 0.f, sn = 0.f, sd = 0.f;
        for (int w = 0; w < 4; w++) { sa += w_a[w]; shh += w_h[w]; sn += w_n[w]; sd += w_d[w]; }
        out[0] = sa / (float)NB;                                        // 1.0 * loss_ratio
        out[1] = (sn > 0.0f) ? 0.1f * (sd / fmaxf(sn, 1.0f)) : 0.0f;    // 0.1 * loss_soft
        out[2] = shh / (float)NB;                                       // 1.0 * loss_hard
    }
}

extern "C" void kernel_launch(void* const* d_in, const int* in_sizes, int n_in,
                              void* d_out, int out_size, void* d_ws, size_t ws_size,
                              hipStream_t stream) {
    const float* imp  = (const float*)d_in[0];
    const int*   mask = (const int*)d_in[1];
    float* out   = (float*)d_out;
    float* stats = (float*)d_ws;   // 256 rows * 4 floats = 4 KB

    dare_rows<<<NB, NT, 0, stream>>>(imp, mask, out, stats);
    dare_losses<<<1, 256, 0, stream>>>(stats, out + (size_t)NB * NS);
}